// Round 7
// baseline (195.793 us; speedup 1.0000x reference)
//
#include <hip/hip_runtime.h>
#include <hip/hip_bf16.h>

// ---------------------------------------------------------------------------
// SemanticActor fused forward, bf16 MFMA (gfx950) — Round 7
// R6 null: launch_bounds 2nd arg = waves/EU, so (512,2)==(512,1); occupancy
// stuck at 8 waves/CU and pipes serialized by 2 barriers/pair lockstep.
// R7: (1) raw B-frags hoisted to registers (bxr[4][4], loaded once) -> GEMM1
// has ZERO LDS reads; (2) Hs double-buffered -> ONE barrier per pair, waves
// in GEMM1 (pure MFMA) overlap waves in GEMM2 (LDS+MFMA); (3) rawS overlaid
// in buf0 (dead after prologue), LDS=64KB; (512,2) -> 256-VGPR cap, GEMM1
// split by col-half to keep peak ~230 VGPR. Watch WRITE_SIZE for spills.
// ---------------------------------------------------------------------------

#define B_TOTAL 65536
#define TROWS   64
#define RSTR    136   // rawS row stride elems (272 B, odd 16B groups)

typedef __attribute__((ext_vector_type(8))) short s8v;   // 8 x bf16
typedef __attribute__((ext_vector_type(4))) float f4v;   // MFMA C/D

__constant__ int c_PI[6] = {0,0,1,1,2,2};
__constant__ int c_PJ[6] = {1,2,0,2,0,1};
__constant__ int c_PF[6] = {0,0,1,0,1,1};
// inverse of FIRST_INDS / SECOND_INDS: raw ag/g col -> X col (or -1)
__constant__ int c_INV[2][30] = {
  {0,1,2,3,4,5,6,7,8,9,10,11,12,13,-1,14,15,16,-1,-1,17,18,-1,-1,-1,19,-1,-1,-1,-1},
  {0,1,2,3,4,5,6,7,8,9,-1,-1,-1,-1,10,-1,-1,-1,11,12,-1,-1,13,14,15,-1,16,17,18,19}};

__global__ void prep_weights(const float* __restrict__ phi_w1,
                             const float* __restrict__ phi_b1,
                             const float* __restrict__ phi_w2,
                             const float* __restrict__ rho_w1,
                             const float* __restrict__ mean_w,
                             const float* __restrict__ logstd_w,
                             __hip_bfloat16* __restrict__ W1P,
                             __hip_bfloat16* __restrict__ W2f,
                             __hip_bfloat16* __restrict__ W3f,
                             __hip_bfloat16* __restrict__ W4f) {
  const int i0 = blockIdx.x * blockDim.x + threadIdx.x;
  const int stride = gridDim.x * blockDim.x;
  // W1P: 6 pairs x (16 nb x 4 ks) x 512; K=128 raw cols via inverse map
  for (int d = i0; d < 6 * 32768; d += stride) {
    int p = d >> 15, r = d & 32767;
    int j = r & 7, lane = (r >> 3) & 63, blk = r >> 9;
    int nb = blk >> 2, ks = blk & 3;
    int n = nb * 16 + (lane & 15), k = ks * 32 + (lane >> 4) * 8 + j;
    int f = c_PF[p], oi = c_PI[p], oj = c_PJ[p];
    float v = 0.0f;
    if (k < 30)       { int t = c_INV[f][k];      if (t >= 0) v = phi_w1[t * 256 + n]; }
    else if (k < 60)  { int t = c_INV[f][k - 30]; if (t >= 0) v = phi_w1[(30 + t) * 256 + n]; }
    else if (k < 70)  { v = phi_w1[(20 + k - 60) * 256 + n]; }
    else if (k < 115) { int q = (k - 70) / 15, t = (k - 70) - q * 15;
                        int c = (q == oi) ? 50 + t : (q == oj) ? 65 + t : -1;
                        if (c >= 0) v = phi_w1[c * 256 + n]; }
    else if (k == 115) v = phi_b1[n];   // bias via ones-column
    W1P[d] = __float2bfloat16(v);
  }
  // W2f/W3f: 16 nb x 8 ks, 256x256
  for (int d = i0; d < 65536; d += stride) {
    int j = d & 7, lane = (d >> 3) & 63, blk = d >> 9;
    int nb = blk >> 3, ks = blk & 7;
    int n = nb * 16 + (lane & 15), k = ks * 32 + (lane >> 4) * 8 + j;
    W2f[d] = __float2bfloat16(phi_w2[k * 256 + n]);
    W3f[d] = __float2bfloat16(rho_w1[k * 256 + n]);
  }
  // W4f: 1 nb (16 head cols: 0-3 mean, 4-7 logstd, rest 0) x 8 ks
  for (int d = i0; d < 4096; d += stride) {
    int j = d & 7, lane = (d >> 3) & 63, ks = d >> 9;
    int n = lane & 15, k = ks * 32 + (lane >> 4) * 8 + j;
    float v = (n < 4) ? mean_w[k * 4 + n]
            : (n < 8) ? logstd_w[k * 4 + (n - 4)] : 0.0f;
    W4f[d] = __float2bfloat16(v);
  }
}

static __device__ __forceinline__ unsigned pk2(float a, float b) {
  __hip_bfloat162 h = __float22bfloat162_rn(float2{a, b});
  union { __hip_bfloat162 h2; unsigned u; } cv; cv.h2 = h;
  return cv.u;
}

// ---- main: 512 threads (8 waves), 64 rows/block, wave = 32-col slice -------
__global__ __launch_bounds__(512, 2)   // 2 waves/EU -> 256 VGPR cap
void actor_main(const float* __restrict__ obs, const float* __restrict__ ag,
                const float* __restrict__ g,
                const __hip_bfloat16* __restrict__ W1P,
                const __hip_bfloat16* __restrict__ W2f,
                const __hip_bfloat16* __restrict__ W3f,
                const __hip_bfloat16* __restrict__ W4f,
                const float* __restrict__ b2, const float* __restrict__ b3,
                const float* __restrict__ meanb,
                const float* __restrict__ logstdb,
                float* __restrict__ out) {
  // double-buffered H (each 4 rt x 8 ks x 512 = 32 KB); rawS overlays buf0
  __shared__ __align__(16) __hip_bfloat16 HsBuf[2][4 * 8 * 512];  // 64 KB

  const int tid  = threadIdx.x;
  const int lane = tid & 63;
  const int w    = tid >> 6;      // wave 0..7 -> hidden cols [32w, 32w+32)
  const int l15  = lane & 15;
  const int quad = lane >> 4;
  const int r0   = blockIdx.x * TROWS;

  float4 b2v[2];
#pragma unroll
  for (int i = 0; i < 2; ++i)
    b2v[i] = *(const float4*)&b2[w * 32 + i * 16 + quad * 4];

  // persistent W2 fragments (once per block)
  s8v w2f[8][2];
#pragma unroll
  for (int i = 0; i < 2; ++i)
#pragma unroll
    for (int ks = 0; ks < 8; ++ks)
      w2f[ks][i] = *(const s8v*)&W2f[(((w * 2 + i) * 8 + ks) * 512) + lane * 8];

  // stage raw input [ag|g|obs|1|0] bf16 K=128 into buf0 overlay (once)
  {
    __hip_bfloat16* rawS = &HsBuf[0][0];
    const int row = tid >> 3;           // 0..63
    const int c0  = (tid & 7) * 16;     // 0..112
    const float* agr = ag  + (size_t)(r0 + row) * 30;
    const float* gr  = g   + (size_t)(r0 + row) * 30;
    const float* obr = obs + (size_t)(r0 + row) * 55;
#pragma unroll
    for (int cc = 0; cc < 16; ++cc) {
      int c = c0 + cc;
      float v;
      if      (c < 30)  v = agr[c];
      else if (c < 60)  v = gr[c - 30];
      else if (c < 115) v = obr[c - 60];
      else if (c == 115) v = 1.0f;
      else              v = 0.0f;
      rawS[row * RSTR + c] = __float2bfloat16(v);
    }
  }
  __syncthreads();

  // hoist raw B-frags to registers: bxr[ks][rt] (64 VGPR, reused 6 pairs x 2i)
  s8v bxr[4][4];
  {
    const __hip_bfloat16* rawS = &HsBuf[0][0];
#pragma unroll
    for (int ks = 0; ks < 4; ++ks)
#pragma unroll
      for (int rt = 0; rt < 4; ++rt)
        bxr[ks][rt] = *(const s8v*)&rawS[(rt * 16 + l15) * RSTR + ks * 32 + quad * 8];
  }
  __syncthreads();  // rawS reads done; buf0 free for pair 0's H

  f4v agg[2][4];
#pragma unroll
  for (int i = 0; i < 2; ++i)
#pragma unroll
    for (int rt = 0; rt < 4; ++rt) agg[i][rt] = f4v{0.f, 0.f, 0.f, 0.f};

  const int ebase = l15 * 8 + (quad >> 1) * 128 + (quad & 1) * 4;

#pragma unroll 1
  for (int p = 0; p < 6; ++p) {
    __hip_bfloat16* buf = &HsBuf[p & 1][0];
    const __hip_bfloat16* w1base = W1P + p * 32768;

    // GEMM1 (registers only), split by col-half i to cap VGPR peak
#pragma unroll
    for (int i = 0; i < 2; ++i) {
      s8v w1f[4];
#pragma unroll
      for (int ks = 0; ks < 4; ++ks)
        w1f[ks] = *(const s8v*)&w1base[(((w * 2 + i) * 4 + ks) * 512) + lane * 8];
      f4v h[4];
#pragma unroll
      for (int rt = 0; rt < 4; ++rt) h[rt] = f4v{0.f, 0.f, 0.f, 0.f};
#pragma unroll
      for (int ks = 0; ks < 4; ++ks)
#pragma unroll
        for (int rt = 0; rt < 4; ++rt)
          h[rt] = __builtin_amdgcn_mfma_f32_16x16x32_bf16(w1f[ks], bxr[ks][rt], h[rt], 0, 0, 0);
      // epilogue: relu (bias folded via ones-column), pack -> b64 write
#pragma unroll
      for (int rt = 0; rt < 4; ++rt) {
        float v0 = fmaxf(h[rt][0], 0.f);
        float v1 = fmaxf(h[rt][1], 0.f);
        float v2 = fmaxf(h[rt][2], 0.f);
        float v3 = fmaxf(h[rt][3], 0.f);
        uint2 U; U.x = pk2(v0, v1); U.y = pk2(v2, v3);
        *reinterpret_cast<uint2*>(&buf[(rt * 8 + w) * 512 + i * 256 + ebase]) = U;
      }
    }
    __syncthreads();  // all H written; prior-pair buffer reads already fenced
                      // by the previous iteration's barrier

    // GEMM2: a2 = W2(A) x H(B); K=256; agg += relu(a2 + b2)
    f4v a2[2][4];
#pragma unroll
    for (int i = 0; i < 2; ++i)
#pragma unroll
      for (int rt = 0; rt < 4; ++rt) a2[i][rt] = f4v{0.f, 0.f, 0.f, 0.f};
#pragma unroll
    for (int ks = 0; ks < 8; ++ks) {
      s8v hf[4];
#pragma unroll
      for (int rt = 0; rt < 4; ++rt)
        hf[rt] = *(const s8v*)&buf[(rt * 8 + ks) * 512 + lane * 8];
#pragma unroll
      for (int i = 0; i < 2; ++i)
#pragma unroll
        for (int rt = 0; rt < 4; ++rt)
          a2[i][rt] = __builtin_amdgcn_mfma_f32_16x16x32_bf16(w2f[ks][i], hf[rt], a2[i][rt], 0, 0, 0);
    }
#pragma unroll
    for (int i = 0; i < 2; ++i)
#pragma unroll
      for (int rt = 0; rt < 4; ++rt) {
        agg[i][rt][0] += fmaxf(a2[i][rt][0] + b2v[i].x, 0.f);
        agg[i][rt][1] += fmaxf(a2[i][rt][1] + b2v[i].y, 0.f);
        agg[i][rt][2] += fmaxf(a2[i][rt][2] + b2v[i].z, 0.f);
        agg[i][rt][3] += fmaxf(a2[i][rt][3] + b2v[i].w, 0.f);
      }
  }
  // NOTE: no barrier needed here — buf0's last readers (GEMM2 of p=4)
  // all passed the p=5 barrier before any wave exits the loop.

  // W3 frags + b3 (loaded late to keep pair-loop VGPR pressure down)
  s8v w3f[8][2];
#pragma unroll
  for (int i = 0; i < 2; ++i)
#pragma unroll
    for (int ks = 0; ks < 8; ++ks)
      w3f[ks][i] = *(const s8v*)&W3f[(((w * 2 + i) * 8 + ks) * 512) + lane * 8];
  float4 b3v[2];
#pragma unroll
  for (int i = 0; i < 2; ++i)
    b3v[i] = *(const float4*)&b3[w * 32 + i * 16 + quad * 4];

  // stash agg (bf16) into buf0, frag-major
  {
    __hip_bfloat16* bufA = &HsBuf[0][0];
#pragma unroll
    for (int i = 0; i < 2; ++i)
#pragma unroll
      for (int rt = 0; rt < 4; ++rt) {
        uint2 U; U.x = pk2(agg[i][rt][0], agg[i][rt][1]);
        U.y = pk2(agg[i][rt][2], agg[i][rt][3]);
        *reinterpret_cast<uint2*>(&bufA[(rt * 8 + w) * 512 + i * 256 + ebase]) = U;
      }
  }
  __syncthreads();

  // GEMM3: hr = relu(W3(A) x agg(B) + b3); K=256; reads buf0, writes buf1
  f4v a3[2][4];
#pragma unroll
  for (int i = 0; i < 2; ++i)
#pragma unroll
    for (int rt = 0; rt < 4; ++rt) a3[i][rt] = f4v{0.f, 0.f, 0.f, 0.f};
  {
    const __hip_bfloat16* bufA = &HsBuf[0][0];
#pragma unroll
    for (int ks = 0; ks < 8; ++ks) {
      s8v hf[4];
#pragma unroll
      for (int rt = 0; rt < 4; ++rt)
        hf[rt] = *(const s8v*)&bufA[(rt * 8 + ks) * 512 + lane * 8];
#pragma unroll
      for (int i = 0; i < 2; ++i)
#pragma unroll
        for (int rt = 0; rt < 4; ++rt)
          a3[i][rt] = __builtin_amdgcn_mfma_f32_16x16x32_bf16(w3f[ks][i], hf[rt], a3[i][rt], 0, 0, 0);
    }
  }
  {
    __hip_bfloat16* bufB = &HsBuf[1][0];
#pragma unroll
    for (int i = 0; i < 2; ++i)
#pragma unroll
      for (int rt = 0; rt < 4; ++rt) {
        float v0 = fmaxf(a3[i][rt][0] + b3v[i].x, 0.f);
        float v1 = fmaxf(a3[i][rt][1] + b3v[i].y, 0.f);
        float v2 = fmaxf(a3[i][rt][2] + b3v[i].z, 0.f);
        float v3 = fmaxf(a3[i][rt][3] + b3v[i].w, 0.f);
        uint2 U; U.x = pk2(v0, v1); U.y = pk2(v2, v3);
        *reinterpret_cast<uint2*>(&bufB[(rt * 8 + w) * 512 + i * 256 + ebase]) = U;
      }
  }
  __syncthreads();

  // GEMM4: heads; waves 0..3 take batch tile rt=w; reads buf1
  if (w < 4) {
    const __hip_bfloat16* bufB = &HsBuf[1][0];
    f4v a4 = f4v{0.f, 0.f, 0.f, 0.f};
#pragma unroll
    for (int ks = 0; ks < 8; ++ks) {
      s8v w4 = *(const s8v*)&W4f[ks * 512 + lane * 8];
      s8v hf = *(const s8v*)&bufB[(w * 8 + ks) * 512 + lane * 8];
      a4 = __builtin_amdgcn_mfma_f32_16x16x32_bf16(w4, hf, a4, 0, 0, 0);
    }
    const int row = r0 + w * 16 + l15;
    if (quad == 0) {          // head cols 0..3 = mean
      float4 mb = *(const float4*)meanb;
      float4 o;
      o.x = a4[0] + mb.x; o.y = a4[1] + mb.y;
      o.z = a4[2] + mb.z; o.w = a4[3] + mb.w;
      *reinterpret_cast<float4*>(&out[(size_t)row * 4]) = o;
    } else if (quad == 1) {   // head cols 4..7 = logstd (clipped)
      float4 lb = *(const float4*)logstdb;
      float4 o;
      o.x = fminf(fmaxf(a4[0] + lb.x, -20.f), 2.f);
      o.y = fminf(fmaxf(a4[1] + lb.y, -20.f), 2.f);
      o.z = fminf(fmaxf(a4[2] + lb.z, -20.f), 2.f);
      o.w = fminf(fmaxf(a4[3] + lb.w, -20.f), 2.f);
      *reinterpret_cast<float4*>(&out[(size_t)B_TOTAL * 4 + (size_t)row * 4]) = o;
    }
  }
}

extern "C" void kernel_launch(void* const* d_in, const int* in_sizes, int n_in,
                              void* d_out, int out_size, void* d_ws, size_t ws_size,
                              hipStream_t stream) {
  const float* obs      = (const float*)d_in[0];
  const float* ag       = (const float*)d_in[1];
  const float* g        = (const float*)d_in[2];
  const float* phi_w1   = (const float*)d_in[3];
  const float* phi_b1   = (const float*)d_in[4];
  const float* phi_w2   = (const float*)d_in[5];
  const float* phi_b2   = (const float*)d_in[6];
  const float* rho_w1   = (const float*)d_in[7];
  const float* rho_b1   = (const float*)d_in[8];
  const float* mean_w   = (const float*)d_in[9];
  const float* mean_b   = (const float*)d_in[10];
  const float* logstd_w = (const float*)d_in[11];
  const float* logstd_b = (const float*)d_in[12];
  float* out = (float*)d_out;

  // ws (bf16): W1P 6x32768 | W2f 65536 | W3f 65536 | W4f 4096 elems
  char* ws = (char*)d_ws;
  __hip_bfloat16* W1P = (__hip_bfloat16*)(ws);
  __hip_bfloat16* W2f = (__hip_bfloat16*)(ws + 393216);
  __hip_bfloat16* W3f = (__hip_bfloat16*)(ws + 393216 + 131072);
  __hip_bfloat16* W4f = (__hip_bfloat16*)(ws + 393216 + 262144);

  prep_weights<<<256, 256, 0, stream>>>(phi_w1, phi_b1, phi_w2, rho_w1,
                                        mean_w, logstd_w, W1P, W2f, W3f, W4f);
  actor_main<<<B_TOTAL / TROWS, 512, 0, stream>>>(
      obs, ag, g, W1P, W2f, W3f, W4f, phi_b2, rho_b1, mean_b, logstd_b, out);
}

// Round 8
// 188.915 us; speedup vs baseline: 1.0364x; 1.0364x over previous
//
#include <hip/hip_runtime.h>
#include <hip/hip_bf16.h>

// ---------------------------------------------------------------------------
// SemanticActor fused forward, bf16 MFMA (gfx950) — Round 8
// R7 analysis: VALUBusy ~= 1.2x MfmaUtil every round -> it mostly counts MFMA
// issue; kernel is MFMA 30% + LDS 30% + stalls. Occupancy pinned ~22% in all
// configs -> 1 block/CU resident -> VGPR budget is effectively 256/wave.
// Bench-kernel gap is a constant ~75us = prep_weights (uncoalesced) + resets.
// R8: (1) prep rewritten: one frag per wave, coalesced reads, b128 writes
// (648 wave-tasks, ~3us); (2) W1P register double-buffer prefetch restored
// (safe under 256-VGPR reality), bxr dropped to pay for it; rawS in own LDS.
// ---------------------------------------------------------------------------

#define B_TOTAL 65536
#define TROWS   64
#define RSTR    136   // rawS row stride elems: 272B = 17x16B -> optimal b128 phasing

typedef __attribute__((ext_vector_type(8))) short s8v;   // 8 x bf16
typedef __attribute__((ext_vector_type(4))) float f4v;   // MFMA C/D

__constant__ int c_PI[6] = {0,0,1,1,2,2};
__constant__ int c_PJ[6] = {1,2,0,2,0,1};
__constant__ int c_PF[6] = {0,0,1,0,1,1};
// inverse of FIRST_INDS / SECOND_INDS: raw ag/g col -> X col (or -1)
__constant__ int c_INV[2][30] = {
  {0,1,2,3,4,5,6,7,8,9,10,11,12,13,-1,14,15,16,-1,-1,17,18,-1,-1,-1,19,-1,-1,-1,-1},
  {0,1,2,3,4,5,6,7,8,9,-1,-1,-1,-1,10,-1,-1,-1,11,12,-1,-1,13,14,15,-1,16,17,18,19}};

static __device__ __forceinline__ short bf16s(float v) {
  __hip_bfloat16 h = __float2bfloat16(v);
  union { __hip_bfloat16 h; short s; } u; u.h = h; return u.s;
}

// ---- prep: one 512-elem fragment per wave; coalesced reads, b128 writes ----
// tasks: [0,384) W1P (p=wid>>6, nb=rem>>2, ks=rem&3) | [384,512) W2f |
//        [512,640) W3f | [640,648) W4f
__global__ __launch_bounds__(256)
void prep_weights(const float* __restrict__ phi_w1,
                  const float* __restrict__ phi_b1,
                  const float* __restrict__ phi_w2,
                  const float* __restrict__ rho_w1,
                  const float* __restrict__ mean_w,
                  const float* __restrict__ logstd_w,
                  __hip_bfloat16* __restrict__ W1P,
                  __hip_bfloat16* __restrict__ W2f,
                  __hip_bfloat16* __restrict__ W3f,
                  __hip_bfloat16* __restrict__ W4f) {
  const int wid  = (blockIdx.x * blockDim.x + threadIdx.x) >> 6;
  const int lane = threadIdx.x & 63;
  const int l15  = lane & 15;
  const int kq   = (lane >> 4) * 8;
  if (wid >= 648) return;
  union { short s[8]; s8v v; } o;
  __hip_bfloat16* dst;
  if (wid < 384) {
    const int p = wid >> 6, rem = wid & 63;
    const int nb = rem >> 2, ks = rem & 3;
    const int n = nb * 16 + l15;
    const int f = c_PF[p], oi = c_PI[p], oj = c_PJ[p];
#pragma unroll
    for (int j = 0; j < 8; ++j) {
      int k = ks * 32 + kq + j;
      float v = 0.0f;
      if (k < 30)       { int t = c_INV[f][k];      if (t >= 0) v = phi_w1[t * 256 + n]; }
      else if (k < 60)  { int t = c_INV[f][k - 30]; if (t >= 0) v = phi_w1[(30 + t) * 256 + n]; }
      else if (k < 70)  { v = phi_w1[(20 + k - 60) * 256 + n]; }
      else if (k < 115) { int q = (k - 70) / 15, t = (k - 70) - q * 15;
                          int c = (q == oi) ? 50 + t : (q == oj) ? 65 + t : -1;
                          if (c >= 0) v = phi_w1[c * 256 + n]; }
      else if (k == 115) v = phi_b1[n];   // bias via ones-column
      o.s[j] = bf16s(v);
    }
    dst = W1P + wid * 512 + lane * 8;
  } else if (wid < 512) {
    const int r = wid - 384;
    const int nb = r >> 3, ks = r & 7;
    const int n = nb * 16 + l15;
#pragma unroll
    for (int j = 0; j < 8; ++j)
      o.s[j] = bf16s(phi_w2[(ks * 32 + kq + j) * 256 + n]);
    dst = W2f + r * 512 + lane * 8;
  } else if (wid < 640) {
    const int r = wid - 512;
    const int nb = r >> 3, ks = r & 7;
    const int n = nb * 16 + l15;
#pragma unroll
    for (int j = 0; j < 8; ++j)
      o.s[j] = bf16s(rho_w1[(ks * 32 + kq + j) * 256 + n]);
    dst = W3f + r * 512 + lane * 8;
  } else {
    const int ks = wid - 640;
    const int n = l15;
#pragma unroll
    for (int j = 0; j < 8; ++j) {
      int k = ks * 32 + kq + j;
      float v = (n < 4) ? mean_w[k * 4 + n]
              : (n < 8) ? logstd_w[k * 4 + (n - 4)] : 0.0f;
      o.s[j] = bf16s(v);
    }
    dst = W4f + ks * 512 + lane * 8;
  }
  *reinterpret_cast<s8v*>(dst) = o.v;
}

static __device__ __forceinline__ unsigned pk2(float a, float b) {
  __hip_bfloat162 h = __float22bfloat162_rn(float2{a, b});
  union { __hip_bfloat162 h2; unsigned u; } cv; cv.h2 = h;
  return cv.u;
}

// ---- main: 512 threads (8 waves), 64 rows/block, wave = 32-col slice -------
__global__ __launch_bounds__(512, 2)
void actor_main(const float* __restrict__ obs, const float* __restrict__ ag,
                const float* __restrict__ g,
                const __hip_bfloat16* __restrict__ W1P,
                const __hip_bfloat16* __restrict__ W2f,
                const __hip_bfloat16* __restrict__ W3f,
                const __hip_bfloat16* __restrict__ W4f,
                const float* __restrict__ b2, const float* __restrict__ b3,
                const float* __restrict__ meanb,
                const float* __restrict__ logstdb,
                float* __restrict__ out) {
  __shared__ __align__(16) __hip_bfloat16 rawS[TROWS * RSTR];      // 34 KB
  __shared__ __align__(16) __hip_bfloat16 HsBuf[2][4 * 8 * 512];   // 64 KB

  const int tid  = threadIdx.x;
  const int lane = tid & 63;
  const int w    = tid >> 6;      // wave 0..7 -> hidden cols [32w, 32w+32)
  const int l15  = lane & 15;
  const int quad = lane >> 4;
  const int r0   = blockIdx.x * TROWS;

  float4 b2v[2];
#pragma unroll
  for (int i = 0; i < 2; ++i)
    b2v[i] = *(const float4*)&b2[w * 32 + i * 16 + quad * 4];

  // persistent W2 fragments (once per block)
  s8v w2f[8][2];
#pragma unroll
  for (int i = 0; i < 2; ++i)
#pragma unroll
    for (int ks = 0; ks < 8; ++ks)
      w2f[ks][i] = *(const s8v*)&W2f[(((w * 2 + i) * 8 + ks) * 512) + lane * 8];

  // stage raw input [ag|g|obs|1|0] bf16 K=128 (vectorized: 2 b128 stores/thread)
  {
    const int row = tid >> 3;           // 0..63
    const int c0  = (tid & 7) * 16;     // 0..112
    const float* agr = ag  + (size_t)(r0 + row) * 30;
    const float* gr  = g   + (size_t)(r0 + row) * 30;
    const float* obr = obs + (size_t)(r0 + row) * 55;
    union { short s[16]; s8v v[2]; } o;
#pragma unroll
    for (int cc = 0; cc < 16; ++cc) {
      int c = c0 + cc;
      float v;
      if      (c < 30)  v = agr[c];
      else if (c < 60)  v = gr[c - 30];
      else if (c < 115) v = obr[c - 60];
      else if (c == 115) v = 1.0f;
      else              v = 0.0f;
      o.s[cc] = bf16s(v);
    }
    *reinterpret_cast<s8v*>(&rawS[row * RSTR + c0])     = o.v[0];
    *reinterpret_cast<s8v*>(&rawS[row * RSTR + c0 + 8]) = o.v[1];
  }

  // preload pair 0's W1P frags
  s8v w1c[4][2], w1n[4][2];
#pragma unroll
  for (int i = 0; i < 2; ++i)
#pragma unroll
    for (int ks = 0; ks < 4; ++ks)
      w1c[ks][i] = *(const s8v*)&W1P[(((w * 2 + i) * 4 + ks) * 512) + lane * 8];

  f4v agg[2][4];
#pragma unroll
  for (int i = 0; i < 2; ++i)
#pragma unroll
    for (int rt = 0; rt < 4; ++rt) agg[i][rt] = f4v{0.f, 0.f, 0.f, 0.f};

  const int ebase = l15 * 8 + (quad >> 1) * 128 + (quad & 1) * 4;

  __syncthreads();  // rawS staged

#pragma unroll 1
  for (int p = 0; p < 6; ++p) {
    __hip_bfloat16* buf = &HsBuf[p & 1][0];

    // prefetch NEXT pair's W1P frags early (consumed only after GEMM2+copy:
    // latency hidden under GEMM1 MFMAs + barrier + GEMM2)
    if (p < 5) {
      const __hip_bfloat16* nb = W1P + (p + 1) * 32768;
#pragma unroll
      for (int i = 0; i < 2; ++i)
#pragma unroll
        for (int ks = 0; ks < 4; ++ks)
          w1n[ks][i] = *(const s8v*)&nb[(((w * 2 + i) * 4 + ks) * 512) + lane * 8];
    }

    // GEMM1: h = W1P[p](A) x raw(B); K=128; raw B-frags from LDS
    f4v h[2][4];
#pragma unroll
    for (int i = 0; i < 2; ++i)
#pragma unroll
      for (int rt = 0; rt < 4; ++rt) h[i][rt] = f4v{0.f, 0.f, 0.f, 0.f};
#pragma unroll
    for (int ks = 0; ks < 4; ++ks) {
      s8v bx[4];
#pragma unroll
      for (int rt = 0; rt < 4; ++rt)
        bx[rt] = *(const s8v*)&rawS[(rt * 16 + l15) * RSTR + ks * 32 + quad * 8];
#pragma unroll
      for (int i = 0; i < 2; ++i)
#pragma unroll
        for (int rt = 0; rt < 4; ++rt)
          h[i][rt] = __builtin_amdgcn_mfma_f32_16x16x32_bf16(w1c[ks][i], bx[rt], h[i][rt], 0, 0, 0);
    }
    // epilogue: relu (bias folded via ones-column), pack -> b64 writes
#pragma unroll
    for (int i = 0; i < 2; ++i)
#pragma unroll
      for (int rt = 0; rt < 4; ++rt) {
        float v0 = fmaxf(h[i][rt][0], 0.f);
        float v1 = fmaxf(h[i][rt][1], 0.f);
        float v2 = fmaxf(h[i][rt][2], 0.f);
        float v3 = fmaxf(h[i][rt][3], 0.f);
        uint2 U; U.x = pk2(v0, v1); U.y = pk2(v2, v3);
        *reinterpret_cast<uint2*>(&buf[(rt * 8 + w) * 512 + i * 256 + ebase]) = U;
      }
    __syncthreads();  // H(p) complete; buf[(p+1)&1]'s old readers fenced by
                      // the previous iteration's barrier

    // GEMM2: a2 = W2(A) x H(B); K=256; agg += relu(a2 + b2)
    f4v a2[2][4];
#pragma unroll
    for (int i = 0; i < 2; ++i)
#pragma unroll
      for (int rt = 0; rt < 4; ++rt) a2[i][rt] = f4v{0.f, 0.f, 0.f, 0.f};
#pragma unroll
    for (int ks = 0; ks < 8; ++ks) {
      s8v hf[4];
#pragma unroll
      for (int rt = 0; rt < 4; ++rt)
        hf[rt] = *(const s8v*)&buf[(rt * 8 + ks) * 512 + lane * 8];
#pragma unroll
      for (int i = 0; i < 2; ++i)
#pragma unroll
        for (int rt = 0; rt < 4; ++rt)
          a2[i][rt] = __builtin_amdgcn_mfma_f32_16x16x32_bf16(w2f[ks][i], hf[rt], a2[i][rt], 0, 0, 0);
    }
#pragma unroll
    for (int i = 0; i < 2; ++i)
#pragma unroll
      for (int rt = 0; rt < 4; ++rt) {
        agg[i][rt][0] += fmaxf(a2[i][rt][0] + b2v[i].x, 0.f);
        agg[i][rt][1] += fmaxf(a2[i][rt][1] + b2v[i].y, 0.f);
        agg[i][rt][2] += fmaxf(a2[i][rt][2] + b2v[i].z, 0.f);
        agg[i][rt][3] += fmaxf(a2[i][rt][3] + b2v[i].w, 0.f);
      }

    // rotate prefetch buffer
    if (p < 5) {
#pragma unroll
      for (int i = 0; i < 2; ++i)
#pragma unroll
        for (int ks = 0; ks < 4; ++ks)
          w1c[ks][i] = w1n[ks][i];
    }
  }

  // W3 frags + b3 (late-loaded)
  s8v w3f[8][2];
#pragma unroll
  for (int i = 0; i < 2; ++i)
#pragma unroll
    for (int ks = 0; ks < 8; ++ks)
      w3f[ks][i] = *(const s8v*)&W3f[(((w * 2 + i) * 8 + ks) * 512) + lane * 8];
  float4 b3v[2];
#pragma unroll
  for (int i = 0; i < 2; ++i)
    b3v[i] = *(const float4*)&b3[w * 32 + i * 16 + quad * 4];

  // stash agg (bf16) into buf0, frag-major (buf0 readers fenced by p=5 barrier)
  {
    __hip_bfloat16* bufA = &HsBuf[0][0];
#pragma unroll
    for (int i = 0; i < 2; ++i)
#pragma unroll
      for (int rt = 0; rt < 4; ++rt) {
        uint2 U; U.x = pk2(agg[i][rt][0], agg[i][rt][1]);
        U.y = pk2(agg[i][rt][2], agg[i][rt][3]);
        *reinterpret_cast<uint2*>(&bufA[(rt * 8 + w) * 512 + i * 256 + ebase]) = U;
      }
  }
  __syncthreads();

  // GEMM3: hr = relu(W3(A) x agg(B) + b3); reads buf0, writes buf1
  f4v a3[2][4];
#pragma unroll
  for (int i = 0; i < 2; ++i)
#pragma unroll
    for (int rt = 0; rt < 4; ++rt) a3[i][rt] = f4v{0.f, 0.f, 0.f, 0.f};
  {
    const __hip_bfloat16* bufA = &HsBuf[0][0];
#pragma unroll
    for (int ks = 0; ks < 8; ++ks) {
      s8v hf[4];
#pragma unroll
      for (int rt = 0; rt < 4; ++rt)
        hf[rt] = *(const s8v*)&bufA[(rt * 8 + ks) * 512 + lane * 8];
#pragma unroll
      for (int i = 0; i < 2; ++i)
#pragma unroll
        for (int rt = 0; rt < 4; ++rt)
          a3[i][rt] = __builtin_amdgcn_mfma_f32_16x16x32_bf16(w3f[ks][i], hf[rt], a3[i][rt], 0, 0, 0);
    }
  }
  {
    __hip_bfloat16* bufB = &HsBuf[1][0];
#pragma unroll
    for (int i = 0; i < 2; ++i)
#pragma unroll
      for (int rt = 0; rt < 4; ++rt) {
        float v0 = fmaxf(a3[i][rt][0] + b3v[i].x, 0.f);
        float v1 = fmaxf(a3[i][rt][1] + b3v[i].y, 0.f);
        float v2 = fmaxf(a3[i][rt][2] + b3v[i].z, 0.f);
        float v3 = fmaxf(a3[i][rt][3] + b3v[i].w, 0.f);
        uint2 U; U.x = pk2(v0, v1); U.y = pk2(v2, v3);
        *reinterpret_cast<uint2*>(&bufB[(rt * 8 + w) * 512 + i * 256 + ebase]) = U;
      }
  }
  __syncthreads();

  // GEMM4: heads; waves 0..3 take batch tile rt=w; reads buf1
  if (w < 4) {
    const __hip_bfloat16* bufB = &HsBuf[1][0];
    f4v a4 = f4v{0.f, 0.f, 0.f, 0.f};
#pragma unroll
    for (int ks = 0; ks < 8; ++ks) {
      s8v w4 = *(const s8v*)&W4f[ks * 512 + lane * 8];
      s8v hf = *(const s8v*)&bufB[(w * 8 + ks) * 512 + lane * 8];
      a4 = __builtin_amdgcn_mfma_f32_16x16x32_bf16(w4, hf, a4, 0, 0, 0);
    }
    const int row = r0 + w * 16 + l15;
    if (quad == 0) {          // head cols 0..3 = mean
      float4 mb = *(const float4*)meanb;
      float4 o;
      o.x = a4[0] + mb.x; o.y = a4[1] + mb.y;
      o.z = a4[2] + mb.z; o.w = a4[3] + mb.w;
      *reinterpret_cast<float4*>(&out[(size_t)row * 4]) = o;
    } else if (quad == 1) {   // head cols 4..7 = logstd (clipped)
      float4 lb = *(const float4*)logstdb;
      float4 o;
      o.x = fminf(fmaxf(a4[0] + lb.x, -20.f), 2.f);
      o.y = fminf(fmaxf(a4[1] + lb.y, -20.f), 2.f);
      o.z = fminf(fmaxf(a4[2] + lb.z, -20.f), 2.f);
      o.w = fminf(fmaxf(a4[3] + lb.w, -20.f), 2.f);
      *reinterpret_cast<float4*>(&out[(size_t)B_TOTAL * 4 + (size_t)row * 4]) = o;
    }
  }
}

extern "C" void kernel_launch(void* const* d_in, const int* in_sizes, int n_in,
                              void* d_out, int out_size, void* d_ws, size_t ws_size,
                              hipStream_t stream) {
  const float* obs      = (const float*)d_in[0];
  const float* ag       = (const float*)d_in[1];
  const float* g        = (const float*)d_in[2];
  const float* phi_w1   = (const float*)d_in[3];
  const float* phi_b1   = (const float*)d_in[4];
  const float* phi_w2   = (const float*)d_in[5];
  const float* phi_b2   = (const float*)d_in[6];
  const float* rho_w1   = (const float*)d_in[7];
  const float* rho_b1   = (const float*)d_in[8];
  const float* mean_w   = (const float*)d_in[9];
  const float* mean_b   = (const float*)d_in[10];
  const float* logstd_w = (const float*)d_in[11];
  const float* logstd_b = (const float*)d_in[12];
  float* out = (float*)d_out;

  // ws (bf16): W1P 6x32768 | W2f 65536 | W3f 65536 | W4f 4096 elems
  char* ws = (char*)d_ws;
  __hip_bfloat16* W1P = (__hip_bfloat16*)(ws);
  __hip_bfloat16* W2f = (__hip_bfloat16*)(ws + 393216);
  __hip_bfloat16* W3f = (__hip_bfloat16*)(ws + 393216 + 131072);
  __hip_bfloat16* W4f = (__hip_bfloat16*)(ws + 393216 + 262144);

  prep_weights<<<162, 256, 0, stream>>>(phi_w1, phi_b1, phi_w2, rho_w1,
                                        mean_w, logstd_w, W1P, W2f, W3f, W4f);
  actor_main<<<B_TOTAL / TROWS, 512, 0, stream>>>(
      obs, ag, g, W1P, W2f, W3f, W4f, phi_b2, rho_b1, mean_b, logstd_b, out);
}